// Round 10
// baseline (327.804 us; speedup 1.0000x reference)
//
#include <hip/hip_runtime.h>

#define SEQ   2048
#define BATCH 4
#define DIM   512
#define VOFF  32768
#define POFF  65536
#define LDS_TOTAL 73728
#define NEG_INF  (-__builtin_inff())

typedef short short8 __attribute__((ext_vector_type(8)));
typedef float floatx4 __attribute__((ext_vector_type(4)));

using lds_char = __attribute__((address_space(3))) char;
using g_void   = const __attribute__((address_space(1))) void;
using l_void   = __attribute__((address_space(3))) void;

__device__ __forceinline__ short to_bf16(float x){
    unsigned u = __float_as_uint(x);
    unsigned r = (u + 0x7fffu + ((u >> 16) & 1u)) >> 16;
    return (short)r;
}

__device__ __forceinline__ float from_bf16(short s){
    unsigned u = ((unsigned)(unsigned short)s) << 16;
    return __uint_as_float(u);
}

__device__ __forceinline__ short8 pack8(floatx4 a, floatx4 b, float s){
    short8 r;
    r[0]=to_bf16(a[0]*s); r[1]=to_bf16(a[1]*s); r[2]=to_bf16(a[2]*s); r[3]=to_bf16(a[3]*s);
    r[4]=to_bf16(b[0]*s); r[5]=to_bf16(b[1]*s); r[6]=to_bf16(b[2]*s); r[7]=to_bf16(b[3]*s);
    return r;
}

// K [k][b][d] fp32 -> Kimg [b][k][d] bf16, per-row 16B-slot XOR swizzle baked in.
extern "C" __global__ void __launch_bounds__(256)
conv_k(const float* __restrict__ K, short* __restrict__ Kimg)
{
    const int t    = blockIdx.x * 256 + threadIdx.x;   // 524288
    const int d8   = t & 63;
    const int row  = t >> 6;                           // k*BATCH + b
    const int k    = row >> 2;
    const int b    = row & 3;
    const float* src = K + (size_t)row * DIM + d8 * 8;
    floatx4 f0 = *(const floatx4*)src;
    floatx4 f1 = *(const floatx4*)(src + 4);
    const int slot = (d8 * 8) ^ ((k & 7) << 3);        // shorts
    *(short8*)(Kimg + ((size_t)b * SEQ + k) * DIM + slot) = pack8(f0, f1, 1.0f);
}

// V [k][b][dv] fp32 -> Vt [b][dv][k] bf16 (transposed, LINEAR — proven).
extern "C" __global__ void __launch_bounds__(256)
conv_v(const float* __restrict__ V, short* __restrict__ Vt)
{
    const int t    = blockIdx.x * 256 + threadIdx.x;   // 524288
    const int dv   = t & 511;
    const int rest = t >> 9;
    const int kc   = rest & 255;
    const int b    = rest >> 8;
    short8 colv;
    #pragma unroll
    for (int i = 0; i < 8; ++i){
        const float f = V[((size_t)(kc*8 + i) * BATCH + b) * DIM + dv];
        colv[i] = to_bf16(f);
    }
    *(short8*)(Vt + ((size_t)b * DIM + dv) * SEQ + kc * 8) = colv;
}

// Combine the two kv-half partials -> final O.
extern "C" __global__ void __launch_bounds__(256)
merge_o(const short* __restrict__ partO, const float* __restrict__ stats,
        float* __restrict__ Og)
{
    const int t = blockIdx.x * 256 + threadIdx.x;      // 4,194,304
    const int d = t & 511;
    const int u = t >> 9;
    const int b = u & 3;
    const int v = u >> 2;                              // global q row 0..2047
    const int qt = v >> 5;
    const int r  = v & 31;
    const int p0 = (qt*4 + b)*2;
    const float O0 = from_bf16(partO[((size_t)p0*32 + r)*512 + d]);
    const float O1 = from_bf16(partO[((size_t)(p0+1)*32 + r)*512 + d]);
    const float m0 = stats[p0*64 + r],        l0 = stats[p0*64 + 32 + r];
    const float m1 = stats[(p0+1)*64 + r],    l1 = stats[(p0+1)*64 + 32 + r];
    const float M  = fmaxf(m0, m1);
    const float a0 = (m0 == NEG_INF) ? 0.f : __expf(m0 - M);
    const float a1 = (m1 == NEG_INF) ? 0.f : __expf(m1 - M);
    const float l  = a0*l0 + a1*l1;
    const float inv = (l > 0.f) ? 1.0f/l : 0.f;
    Og[((size_t)v*BATCH + b)*DIM + d] = (a0*O0 + a1*O1) * inv;
}

extern "C" __global__ void __launch_bounds__(512, 4)
fa_fwd(const float* __restrict__ Qg, const short* __restrict__ Kb,
       const short* __restrict__ Vt, const unsigned char* __restrict__ Mg,
       short* __restrict__ partO, float* __restrict__ stats)
{
    extern __shared__ __align__(16) char smem[];
    const int tid  = threadIdx.x;
    const int w    = tid >> 6;        // 0..7
    const int lane = tid & 63;
    const int g    = lane >> 4;
    const int c    = lane & 15;
    const int qhalf = w & 1;
    const int dvq   = w >> 1;         // dv quarter 0..3

    // slot -> XCD; batch pinned to an XCD pair; qt paired j <-> 63-j so the
    // two co-resident blocks per CU sum to ~uniform kv work.
    const int slot = blockIdx.x & 7;
    const int idx  = blockIdx.x >> 3;           // 0..63
    const int b    = slot >> 1;
    const int h    = slot & 1;                  // kv half
    const int qt   = (idx & 1) ? (63 - (idx >> 1)) : (idx >> 1);

    const int q0 = qt * 32;
    const int ntiles = qt + 1;
    const int n0     = (ntiles + 1) >> 1;
    const int start  = h ? n0 : 0;
    const int cnt    = h ? (ntiles - n0) : n0;
    const int p      = (qt*4 + b)*2 + h;

    char* kbuf = smem;                 // [32 k][512 d] bf16, swizzled image
    char* vbuf = smem + VOFF;          // [512 dv][32 k] bf16, linear
    char* Pb   = smem + POFF + w*1024; // per-wave P [16 q][32 k]

    const short* Kbb = Kb + (size_t)b * SEQ * DIM;
    const short* Vtb = Vt + (size_t)b * DIM * SEQ;

    // ---- Q -> registers (bf16, pre-scaled by 1/sqrt(D)) ----
    const float scale = 0.04419417382415922f;  // 1/sqrt(512)
    short8 qreg[16];
    {
        const float* qrow = Qg + ((size_t)(q0 + qhalf*16 + c) * BATCH + b) * DIM + g * 8;
        #pragma unroll
        for (int ks = 0; ks < 16; ++ks){
            floatx4 f0 = *(const floatx4*)(qrow + ks*32);
            floatx4 f1 = *(const floatx4*)(qrow + ks*32 + 4);
            qreg[ks] = pack8(f0, f1, scale);
        }
    }

    floatx4 oacc[8];
    #pragma unroll
    for (int i=0;i<8;++i){ floatx4 z = {0.f,0.f,0.f,0.f}; oacc[i]=z; }
    float mrow[4] = {NEG_INF, NEG_INF, NEG_INF, NEG_INF};
    float lrow[4] = {0.f,0.f,0.f,0.f};

    // wave w stages K rows [w*4, w*4+4) and V dv-rows [w*64, w*64+64)
    #define STAGE_K(tt) { \
        const short* ksrc_ = Kbb + ((size_t)((tt)*32 + w*4)) * DIM + lane*8; \
        char* ldst_ = kbuf + w*4096; \
        _Pragma("unroll") \
        for (int i_ = 0; i_ < 4; ++i_) \
            __builtin_amdgcn_global_load_lds((g_void*)(ksrc_ + (size_t)i_*DIM), \
                                             (l_void*)(lds_char*)(ldst_ + i_*1024), 16, 0, 0); }

    #define STAGE_V(tt) { \
        char* ldst_ = vbuf + w*4096; \
        _Pragma("unroll") \
        for (int i_ = 0; i_ < 4; ++i_){ \
            const short* vsrc_ = Vtb + (size_t)(w*64 + i_*16 + (lane>>2))*SEQ \
                               + (tt)*32 + (lane&3)*8; \
            __builtin_amdgcn_global_load_lds((g_void*)vsrc_, \
                                             (l_void*)(lds_char*)(ldst_ + i_*1024), 16, 0, 0); } }

    if (cnt > 0){ STAGE_K(start); STAGE_V(start); }

    for (int i = 0; i < cnt; ++i){
        const int tt = start + i;
        const int kb = tt * 32;

        asm volatile("s_waitcnt vmcnt(0)" ::: "memory");
        __syncthreads();   // [A] K(tt), V(tt) landed & visible

        // ---- S = Q K^T (full 32 kcols per wave; redundant across dvq) ----
        floatx4 sacc[2];
        { floatx4 z = {0.f,0.f,0.f,0.f}; sacc[0]=z; sacc[1]=z; }
        const unsigned char km0 = Mg[(kb + c) * BATCH + b];
        const unsigned char km1 = Mg[(kb + 16 + c) * BATCH + b];
        #pragma unroll
        for (int ks = 0; ks < 16; ++ks){
            #pragma unroll
            for (int nt = 0; nt < 2; ++nt){
                const int kcol = nt*16 + c;
                short8 kf = *(const short8*)(kbuf + kcol*1024 +
                               ((ks*64 + g*16) ^ ((kcol & 7) << 4)));
                sacc[nt] = __builtin_amdgcn_mfma_f32_16x16x32_bf16(qreg[ks], kf, sacc[nt], 0,0,0);
            }
        }

        __syncthreads();   // [B] K reads done -> restage K

        if (i + 1 < cnt) STAGE_K(tt + 1);

        // ---- mask + online softmax (C layout: row=g*4+jj, col=nt*16+c) ----
        float s[2][4];
        #pragma unroll
        for (int nt = 0; nt < 2; ++nt){
            const int col = kb + nt*16 + c;
            const unsigned char km = nt ? km1 : km0;
            #pragma unroll
            for (int jj = 0; jj < 4; ++jj){
                const int row = q0 + qhalf*16 + g*4 + jj;
                s[nt][jj] = (col > row || km) ? NEG_INF : sacc[nt][jj];
            }
        }
        float pmax[4];
        #pragma unroll
        for (int jj=0;jj<4;++jj) pmax[jj] = fmaxf(s[0][jj], s[1][jj]);
        #pragma unroll
        for (int msk=1; msk<16; msk<<=1){
            #pragma unroll
            for (int jj=0;jj<4;++jj)
                pmax[jj] = fmaxf(pmax[jj], __shfl_xor(pmax[jj], msk, 64));
        }
        const bool okd = (pmax[0] <= mrow[0]+8.f) && (pmax[1] <= mrow[1]+8.f)
                      && (pmax[2] <= mrow[2]+8.f) && (pmax[3] <= mrow[3]+8.f);
        if (!__all(okd)){
            float fsc[4];
            #pragma unroll
            for (int jj=0;jj<4;++jj){
                const float M = fmaxf(mrow[jj], pmax[jj]);
                const float f = (mrow[jj] == NEG_INF) ? 0.f : __expf(mrow[jj] - M);
                mrow[jj] = M; lrow[jj] *= f; fsc[jj] = f;
            }
            #pragma unroll
            for (int nt=0; nt<8; ++nt){
                #pragma unroll
                for (int jj=0; jj<4; ++jj) oacc[nt][jj] *= fsc[jj];
            }
        }
        float parr[2][4], psum[4] = {0.f,0.f,0.f,0.f};
        #pragma unroll
        for (int nt=0; nt<2; ++nt){
            #pragma unroll
            for (int jj=0; jj<4; ++jj){
                const float sv = s[nt][jj];
                const float e = (sv == NEG_INF) ? 0.f : __expf(sv - mrow[jj]);
                parr[nt][jj] = e; psum[jj] += e;
            }
        }
        #pragma unroll
        for (int msk=1; msk<16; msk<<=1){
            #pragma unroll
            for (int jj=0;jj<4;++jj) psum[jj] += __shfl_xor(psum[jj], msk, 64);
        }
        #pragma unroll
        for (int jj=0;jj<4;++jj) lrow[jj] += psum[jj];

        // ---- P [16q][32k] in per-wave LDS (no cross-wave dep) ----
        #pragma unroll
        for (int nt=0; nt<2; ++nt){
            #pragma unroll
            for (int jj=0; jj<4; ++jj)
                *(short*)(Pb + (g*4 + jj)*64 + (nt*16 + c)*2) = to_bf16(parr[nt][jj]);
        }

        // ---- O += P V on this wave's dv quarter (8 dv-tiles) ----
        const short8 pfrag = *(const short8*)(Pb + c*64 + g*16);
        #pragma unroll
        for (int nt = 0; nt < 8; ++nt){
            const int dv = dvq*128 + nt*16 + c;
            const short8 vfr = *(const short8*)(vbuf + dv*64 + g*16);
            oacc[nt] = __builtin_amdgcn_mfma_f32_16x16x32_bf16(pfrag, vfr, oacc[nt], 0,0,0);
        }

        __syncthreads();   // [C] V reads done -> restage V

        if (i + 1 < cnt) STAGE_V(tt + 1);
    }
    #undef STAGE_K
    #undef STAGE_V

    // ---- write this block's partial (numerator O as bf16, stats fp32) ----
    {
        short* po = partO + (size_t)p * 32 * 512;
        #pragma unroll
        for (int nt = 0; nt < 8; ++nt){
            #pragma unroll
            for (int jj = 0; jj < 4; ++jj){
                const int R  = qhalf*16 + g*4 + jj;
                const int dv = dvq*128 + nt*16 + c;
                po[(size_t)R*512 + dv] = to_bf16(oacc[nt][jj]);
            }
        }
        if (dvq == 0 && c == 0){
            #pragma unroll
            for (int jj = 0; jj < 4; ++jj){
                const int R = qhalf*16 + g*4 + jj;
                stats[p*64 + R]      = mrow[jj];
                stats[p*64 + 32 + R] = lrow[jj];
            }
        }
    }
}

extern "C" void kernel_launch(void* const* d_in, const int* in_sizes, int n_in,
                              void* d_out, int out_size, void* d_ws, size_t ws_size,
                              hipStream_t stream)
{
    const float* Q = (const float*)d_in[0];
    const float* K = (const float*)d_in[1];
    const float* V = (const float*)d_in[2];
    const unsigned char* M = (const unsigned char*)d_in[3];
    float* O = (float*)d_out;
    (void)in_sizes; (void)n_in; (void)out_size; (void)ws_size;

    short* Kb    = (short*)d_ws;                            // 8 MB swizzled K image
    short* Vt    = Kb + (size_t)BATCH * SEQ * DIM;          // 8 MB linear V^T image
    short* partO = Vt + (size_t)BATCH * SEQ * DIM;          // 16 MB bf16 partials
    float* stats = (float*)(partO + (size_t)512 * 32 * 512);// 128 KB m/l

    conv_k<<<2048, 256, 0, stream>>>(K, Kb);
    conv_v<<<2048, 256, 0, stream>>>(V, Vt);

    hipFuncSetAttribute(reinterpret_cast<const void*>(fa_fwd),
                        hipFuncAttributeMaxDynamicSharedMemorySize, LDS_TOTAL);
    fa_fwd<<<512, 512, LDS_TOTAL, stream>>>(Q, Kb, Vt, M, partO, stats);

    merge_o<<<16384, 256, 0, stream>>>(partO, stats, O);
}

// Round 11
// 145.186 us; speedup vs baseline: 2.2578x; 2.2578x over previous
//
#include <hip/hip_runtime.h>

#define SEQ   2048
#define BATCH 4
#define DIM   512
#define P_OFF    65536
#define STAT_OFF 67584
#define LDS_TOTAL 69632
#define NEG_INF  (-__builtin_inff())

typedef short short8 __attribute__((ext_vector_type(8)));
typedef float floatx4 __attribute__((ext_vector_type(4)));

using lds_char = __attribute__((address_space(3))) char;
using g_void   = const __attribute__((address_space(1))) void;
using l_void   = __attribute__((address_space(3))) void;

__device__ __forceinline__ short to_bf16(float x){
    unsigned u = __float_as_uint(x);
    unsigned r = (u + 0x7fffu + ((u >> 16) & 1u)) >> 16;
    return (short)r;
}

__device__ __forceinline__ short8 pack8(floatx4 a, floatx4 b, float s){
    short8 r;
    r[0]=to_bf16(a[0]*s); r[1]=to_bf16(a[1]*s); r[2]=to_bf16(a[2]*s); r[3]=to_bf16(a[3]*s);
    r[4]=to_bf16(b[0]*s); r[5]=to_bf16(b[1]*s); r[6]=to_bf16(b[2]*s); r[7]=to_bf16(b[3]*s);
    return r;
}

// K [k][b][d] fp32 -> Kimg [b][k][d] bf16, per-row 16B-slot XOR swizzle baked in.
extern "C" __global__ void __launch_bounds__(256)
conv_k(const float* __restrict__ K, short* __restrict__ Kimg)
{
    const int t    = blockIdx.x * 256 + threadIdx.x;   // 524288
    const int d8   = t & 63;
    const int row  = t >> 6;                           // k*BATCH + b
    const int k    = row >> 2;
    const int b    = row & 3;
    const float* src = K + (size_t)row * DIM + d8 * 8;
    floatx4 f0 = *(const floatx4*)src;
    floatx4 f1 = *(const floatx4*)(src + 4);
    const int slot = (d8 * 8) ^ ((k & 7) << 3);        // shorts
    *(short8*)(Kimg + ((size_t)b * SEQ + k) * DIM + slot) = pack8(f0, f1, 1.0f);
}

// V [k][b][dv] fp32 -> Vt [b][dv][k] bf16 (transposed, LINEAR — proven).
extern "C" __global__ void __launch_bounds__(256)
conv_v(const float* __restrict__ V, short* __restrict__ Vt)
{
    const int t    = blockIdx.x * 256 + threadIdx.x;   // 524288
    const int dv   = t & 511;
    const int rest = t >> 9;
    const int kc   = rest & 255;
    const int b    = rest >> 8;
    short8 colv;
    #pragma unroll
    for (int i = 0; i < 8; ++i){
        const float f = V[((size_t)(kc*8 + i) * BATCH + b) * DIM + dv];
        colv[i] = to_bf16(f);
    }
    *(short8*)(Vt + ((size_t)b * DIM + dv) * SEQ + kc * 8) = colv;
}

extern "C" __global__ void __launch_bounds__(256, 2)
fa_fwd(const float* __restrict__ Qg, const short* __restrict__ Kb,
       const short* __restrict__ Vt, const unsigned char* __restrict__ Mg,
       float* __restrict__ Og)
{
    extern __shared__ __align__(16) char smem[];
    const int tid  = threadIdx.x;
    const int w    = tid >> 6;        // 0..3
    const int lane = tid & 63;
    const int g    = lane >> 4;
    const int c    = lane & 15;
    const int par  = w >> 1;          // kv parity 0/1
    const int dvh  = w & 1;           // dv half 0/1

    // slot -> XCD (batch pinned to XCD pair); qt via a two-way-hedged
    // involution so either plausible co-residency pairing ((2m,2m+1) or
    // (i,i+32)) gives qt + qt' ~ 63 -> uniform per-CU kv work.
    const int slot = blockIdx.x & 7;
    const int idx  = blockIdx.x >> 3;            // 0..63
    const int b    = slot >> 1;
    const int u    = slot & 1;                   // q half (16 rows)
    const int p_   = idx & 1;
    const int s_   = (idx >> 5) & 1;
    const int mm   = (idx >> 1) & 15;
    const int tq   = mm + (s_ << 4);
    const int qt   = (p_ ^ s_) ? 63 - tq : tq;   // 0..63, bijective

    const int q0 = qt * 32 + u * 16;
    const int ntiles = qt + 1;
    const int iters  = (ntiles + 1) >> 1;

    char* buf = smem + par * 32768;    // K(t) then V(t) for this parity
    char* Pb  = smem + P_OFF + par * 1024;

    const short* Kbb = Kb + (size_t)b * SEQ * DIM;
    const short* Vtb = Vt + (size_t)b * DIM * SEQ;

    // ---- Q -> registers (bf16, pre-scaled by 1/sqrt(D)) ----
    const float scale = 0.04419417382415922f;  // 1/sqrt(512)
    short8 qreg[16];
    {
        const float* qrow = Qg + ((size_t)(q0 + c) * BATCH + b) * DIM + g * 8;
        #pragma unroll
        for (int ks = 0; ks < 16; ++ks){
            floatx4 f0 = *(const floatx4*)(qrow + ks*32);
            floatx4 f1 = *(const floatx4*)(qrow + ks*32 + 4);
            qreg[ks] = pack8(f0, f1, scale);
        }
    }

    floatx4 oacc[16];
    #pragma unroll
    for (int i=0;i<16;++i){ floatx4 z = {0.f,0.f,0.f,0.f}; oacc[i]=z; }
    float mrow[4] = {NEG_INF, NEG_INF, NEG_INF, NEG_INF};
    float lrow[4] = {0.f,0.f,0.f,0.f};

    // wave (par,dvh) stages K rows [dvh*16, dvh*16+16) of tile tt (16 KB)
    #define STAGE_K(tt) { \
        const short* ksrc_ = Kbb + ((size_t)((tt)*32 + dvh*16)) * DIM + lane*8; \
        char* ldst_ = buf + dvh*16384; \
        _Pragma("unroll") \
        for (int i_ = 0; i_ < 16; ++i_) \
            __builtin_amdgcn_global_load_lds((g_void*)(ksrc_ + (size_t)i_*DIM), \
                                             (l_void*)(lds_char*)(ldst_ + i_*1024), 16, 0, 0); }

    // wave (par,dvh) stages V dv rows [dvh*256, +256): source pre-swizzled
    // (chunk = (lane&3) ^ (lane>>4)) so linear LDS dest yields the proven
    // slot ^ ((dv>>2)&3) layout read by PV.
    #define STAGE_V(tt) { \
        const int q8_ = (lane & 3) ^ (lane >> 4); \
        char* ldst_ = buf + dvh*16384; \
        _Pragma("unroll") \
        for (int i_ = 0; i_ < 16; ++i_){ \
            const short* vsrc_ = Vtb + (size_t)(dvh*256 + i_*16 + (lane>>2))*SEQ \
                               + (tt)*32 + q8_*8; \
            __builtin_amdgcn_global_load_lds((g_void*)vsrc_, \
                                             (l_void*)(lds_char*)(ldst_ + i_*1024), 16, 0, 0); } }

    if (par < ntiles) STAGE_K(par);

    for (int i = 0; i < iters; ++i){
        const int t  = 2*i + par;
        const int kb = t * 32;
        const bool active = (t < ntiles);

        asm volatile("s_waitcnt vmcnt(0)" ::: "memory");
        __syncthreads();   // [A] K(t) landed & visible

        floatx4 sacc[2];
        { floatx4 z = {0.f,0.f,0.f,0.f}; sacc[0]=z; sacc[1]=z; }
        unsigned char km0 = 0, km1 = 0;
        if (active){
            km0 = Mg[(kb + c) * BATCH + b];
            km1 = Mg[(kb + 16 + c) * BATCH + b];
            #pragma unroll
            for (int ks = 0; ks < 16; ++ks){
                #pragma unroll
                for (int nt = 0; nt < 2; ++nt){
                    const int kcol = nt*16 + c;
                    short8 kf = *(const short8*)(buf + kcol*1024 +
                                   ((ks*64 + g*16) ^ ((kcol & 7) << 4)));
                    sacc[nt] = __builtin_amdgcn_mfma_f32_16x16x32_bf16(qreg[ks], kf, sacc[nt], 0,0,0);
                }
            }
        }

        __syncthreads();   // [B] K reads done -> buf reusable for V

        if (active) STAGE_V(t);

        if (active){
            // ---- mask + online softmax (redundant across dvh, identical) ----
            float s[2][4];
            #pragma unroll
            for (int nt = 0; nt < 2; ++nt){
                const int col = kb + nt*16 + c;
                const unsigned char km = nt ? km1 : km0;
                #pragma unroll
                for (int jj = 0; jj < 4; ++jj){
                    const int row = q0 + g*4 + jj;
                    s[nt][jj] = (col > row || km) ? NEG_INF : sacc[nt][jj];
                }
            }
            float pmax[4];
            #pragma unroll
            for (int jj=0;jj<4;++jj) pmax[jj] = fmaxf(s[0][jj], s[1][jj]);
            #pragma unroll
            for (int msk=1; msk<16; msk<<=1){
                #pragma unroll
                for (int jj=0;jj<4;++jj)
                    pmax[jj] = fmaxf(pmax[jj], __shfl_xor(pmax[jj], msk, 64));
            }
            const bool okd = (pmax[0] <= mrow[0]+8.f) && (pmax[1] <= mrow[1]+8.f)
                          && (pmax[2] <= mrow[2]+8.f) && (pmax[3] <= mrow[3]+8.f);
            if (!__all(okd)){
                float fsc[4];
                #pragma unroll
                for (int jj=0;jj<4;++jj){
                    const float M = fmaxf(mrow[jj], pmax[jj]);
                    const float f = (mrow[jj] == NEG_INF) ? 0.f : __expf(mrow[jj] - M);
                    mrow[jj] = M; lrow[jj] *= f; fsc[jj] = f;
                }
                #pragma unroll
                for (int nt=0; nt<16; ++nt){
                    #pragma unroll
                    for (int jj=0; jj<4; ++jj) oacc[nt][jj] *= fsc[jj];
                }
            }
            float parr[2][4], psum[4] = {0.f,0.f,0.f,0.f};
            #pragma unroll
            for (int nt=0; nt<2; ++nt){
                #pragma unroll
                for (int jj=0; jj<4; ++jj){
                    const float sv = s[nt][jj];
                    const float e = (sv == NEG_INF) ? 0.f : __expf(sv - mrow[jj]);
                    parr[nt][jj] = e; psum[jj] += e;
                }
            }
            #pragma unroll
            for (int msk=1; msk<16; msk<<=1){
                #pragma unroll
                for (int jj=0;jj<4;++jj) psum[jj] += __shfl_xor(psum[jj], msk, 64);
            }
            #pragma unroll
            for (int jj=0;jj<4;++jj) lrow[jj] += psum[jj];

            // ---- P [16q][32k] (dvh==0 wave writes; identical values) ----
            if (dvh == 0){
                #pragma unroll
                for (int nt=0; nt<2; ++nt){
                    #pragma unroll
                    for (int jj=0; jj<4; ++jj)
                        *(short*)(Pb + (g*4 + jj)*64 + (nt*16 + c)*2) = to_bf16(parr[nt][jj]);
                }
            }
        }

        asm volatile("s_waitcnt vmcnt(0)" ::: "memory");
        __syncthreads();   // [C] V(t) landed + P visible

        if (active){
            // ---- O += P V on this wave's dv half (16 dv-tiles) ----
            const short8 pfrag = *(const short8*)(Pb + c*64 + g*16);
            #pragma unroll
            for (int nt = 0; nt < 16; ++nt){
                const int dv = dvh*256 + nt*16 + c;
                const short8 vfr = *(const short8*)(buf + dv*64 +
                                      ((g ^ ((dv >> 2) & 3)) << 4));
                oacc[nt] = __builtin_amdgcn_mfma_f32_16x16x32_bf16(pfrag, vfr, oacc[nt], 0,0,0);
            }
        }

        __syncthreads();   // [D] V reads done -> buf reusable for K(t+2)

        if (t + 2 < ntiles) STAGE_K(t + 2);
    }
    #undef STAGE_K
    #undef STAGE_V

    // ---- merge the 2 kv-parity partials (per dv half) ----
    __syncthreads();
    if (par == 1){
        float* ox = (float*)(smem + dvh*16384);
        #pragma unroll
        for (int nt=0; nt<16; ++nt){
            #pragma unroll
            for (int jj=0; jj<4; ++jj) ox[(nt*4 + jj)*64 + lane] = oacc[nt][jj];
        }
        if (dvh == 0){
            float* st = (float*)(smem + STAT_OFF);
            #pragma unroll
            for (int jj=0; jj<4; ++jj){
                st[jj*64 + lane] = mrow[jj];
                st[(4+jj)*64 + lane] = lrow[jj];
            }
        }
    }
    __syncthreads();
    if (par == 0){
        const float* ox = (const float*)(smem + dvh*16384);
        const float* st = (const float*)(smem + STAT_OFF);
        #pragma unroll
        for (int jj=0; jj<4; ++jj){
            const float m2 = st[jj*64 + lane];
            const float l2 = st[(4+jj)*64 + lane];
            const float M  = fmaxf(mrow[jj], m2);
            const float a1 = (mrow[jj] == NEG_INF) ? 0.f : __expf(mrow[jj] - M);
            const float a2 = (m2       == NEG_INF) ? 0.f : __expf(m2 - M);
            const float L  = a1*lrow[jj] + a2*l2;
            const float inv = (L > 0.f) ? 1.0f / L : 0.f;
            float* orow = Og + ((size_t)(q0 + g*4 + jj) * BATCH + b) * DIM + dvh*256 + c;
            #pragma unroll
            for (int nt=0; nt<16; ++nt){
                const float o2 = ox[(nt*4 + jj)*64 + lane];
                orow[nt*16] = (a1*oacc[nt][jj] + a2*o2) * inv;
            }
        }
    }
}

extern "C" void kernel_launch(void* const* d_in, const int* in_sizes, int n_in,
                              void* d_out, int out_size, void* d_ws, size_t ws_size,
                              hipStream_t stream)
{
    const float* Q = (const float*)d_in[0];
    const float* K = (const float*)d_in[1];
    const float* V = (const float*)d_in[2];
    const unsigned char* M = (const unsigned char*)d_in[3];
    float* O = (float*)d_out;
    (void)in_sizes; (void)n_in; (void)out_size; (void)ws_size;

    short* Kb = (short*)d_ws;                               // 8 MB swizzled K image
    short* Vt = Kb + (size_t)BATCH * SEQ * DIM;             // 8 MB linear V^T image

    conv_k<<<2048, 256, 0, stream>>>(K, Kb);
    conv_v<<<2048, 256, 0, stream>>>(V, Vt);

    hipFuncSetAttribute(reinterpret_cast<const void*>(fa_fwd),
                        hipFuncAttributeMaxDynamicSharedMemorySize, LDS_TOTAL);
    fa_fwd<<<512, 256, LDS_TOTAL, stream>>>(Q, Kb, Vt, M, O);
}